// Round 10
// baseline (286.444 us; speedup 1.0000x reference)
//
#include <hip/hip_runtime.h>

typedef __bf16 bf16;
typedef __attribute__((ext_vector_type(8))) __bf16 bf16x8;
typedef __attribute__((ext_vector_type(4))) __bf16 bf16x4;
typedef __attribute__((ext_vector_type(4))) float f32x4;

static __device__ __forceinline__ f32x4 mfma16(bf16x8 a, bf16x8 b, f32x4 c) {
    return __builtin_amdgcn_mfma_f32_16x16x32_bf16(a, b, c, 0, 0, 0);
}

// async global->LDS, 16B per lane; lds base must be wave-uniform
static __device__ __forceinline__ void gll16(const bf16* g, bf16* l) {
    __builtin_amdgcn_global_load_lds(
        (const __attribute__((address_space(1))) unsigned int*)g,
        (__attribute__((address_space(3))) unsigned int*)l, 16, 0, 0);
}

// =====================================================================
// Fused prep: xcvt (blocks 0..4095) | wtrans (4096..5119) | biascat (5120..5131)
// =====================================================================
__global__ __launch_bounds__(256) void prep_kernel(
    const float* __restrict__ x, bf16* __restrict__ xb,
    const float* __restrict__ Wq, const float* __restrict__ Wk,
    const float* __restrict__ Wv, const float* __restrict__ Wo,
    bf16* __restrict__ WTqkv, bf16* __restrict__ WTo,
    const float* __restrict__ bq, const float* __restrict__ bk,
    const float* __restrict__ bv, float* __restrict__ bcat)
{
    __shared__ bf16 tile[64][65];
    const int bid = blockIdx.x;
    const int tid = threadIdx.x;

    if (bid < 4096) {
        size_t i = ((size_t)bid * 256 + tid) * 8;
        float4 a0 = *(const float4*)&x[i];
        float4 a1 = *(const float4*)&x[i + 4];
        bf16x8 v = {(bf16)a0.x, (bf16)a0.y, (bf16)a0.z, (bf16)a0.w,
                    (bf16)a1.x, (bf16)a1.y, (bf16)a1.z, (bf16)a1.w};
        *(bf16x8*)&xb[i] = v;
    } else if (bid < 5120) {
        const int wb = bid - 4096;
        const int mi = wb >> 8;
        const int t  = wb & 255;
        const int tr = t >> 4;
        const int tc = t & 15;
        const float* src = (mi == 0) ? Wq : (mi == 1) ? Wk : (mi == 2) ? Wv : Wo;
        bf16* dst = (mi < 3) ? (WTqkv + (size_t)mi * 1024 * 1024) : WTo;

        #pragma unroll
        for (int i = 0; i < 16; i++) {
            int idx = i * 256 + tid;
            int rl = idx >> 6, cl = idx & 63;
            tile[rl][cl] = (bf16)src[(size_t)(tr * 64 + rl) * 1024 + tc * 64 + cl];
        }
        __syncthreads();
        #pragma unroll
        for (int i = 0; i < 16; i++) {
            int idx = i * 256 + tid;
            int rl = idx >> 6, cl = idx & 63;
            dst[(size_t)(tc * 64 + rl) * 1024 + tr * 64 + cl] = tile[cl][rl];
        }
    } else {
        int i = (bid - 5120) * 256 + tid;
        if (i < 1024) bcat[i] = bq[i];
        else if (i < 2048) bcat[i] = bk[i - 1024];
        else if (i < 3072) bcat[i] = bv[i - 2048];
    }
}

// =====================================================================
// QKV GEMM — Round-9 rewrite: counted-vmcnt phase schedule (T3+T4).
// BM=128 x BN=256 x BK=64, 512 thr (8 waves, 2Mx4N, 64x64 out/wave),
// LDS 96KB dbuf, grid 12x64=768 (3 even rounds on 256 CUs).
// Per K-tile: 2 phases of 16 MFMA (N-split quadrants, A-frags reused).
// Staging: 2 gll16/phase + 2 at iter end; asm vmcnt(2) ONLY at iter
// boundary (2 loads stay in flight across the raw s_barrier; no
// __syncthreads drain in the main loop).  T2 swizzle g^=(row&7):
// thread-constant on both stage-source and read side, conflict-free.
// V-blocks (n0>=2048) transpose via LDS (sB reuse) straight to Vt.
// =====================================================================
#define QSCALE 0.18033688011112043f   // 0.125 * log2(e)
__global__ __launch_bounds__(512, 2) void gemm_qkv_kernel(
    const bf16* __restrict__ A, const bf16* __restrict__ BT,
    const float* __restrict__ bias, bf16* __restrict__ C,
    bf16* __restrict__ Vt)
{
    __shared__ bf16 sA[2 * 8192];     // [buf][128 rows][64 k]
    __shared__ bf16 sB[2 * 16384];    // [buf][256 rows][64 k]; reused for V-transpose

    const int tid  = threadIdx.x;
    const int lane = tid & 63;
    const int wave = tid >> 6;        // 0..7
    const int wm   = wave >> 2;       // 0..1  (M half)
    const int wn   = wave & 3;        // 0..3  (N quarter)
    const int quad = lane >> 4;
    const int l15  = lane & 15;
    const int gx   = l15 & 7;         // read-side swizzle key
    const int m0 = blockIdx.y * 128;
    const int n0 = blockIdx.x * 256;
    const int K = 1024;
    const int N = 3072;

    const int srow8 = lane >> 3;                   // 0..7 (row-within-8 on stage)
    const int scol  = ((lane & 7) ^ srow8) * 8;    // pre-swizzled source col

// stage load L (rows L*64 + wave*8 + srow8) of K-tile T
#define S_A(L, T)                                                                  \
    gll16(&A[(size_t)(m0 + (L) * 64 + wave * 8 + srow8) * K + (T) * 64 + scol],    \
          &sA[((T) & 1) * 8192 + ((L) * 64 + wave * 8) * 64])
#define S_B(L, T)                                                                  \
    gll16(&BT[(size_t)(n0 + (L) * 64 + wave * 8 + srow8) * K + (T) * 64 + scol],   \
          &sB[((T) & 1) * 16384 + ((L) * 64 + wave * 8) * 64])

    const f32x4 fzero = {0.f, 0.f, 0.f, 0.f};
    f32x4 acc[4][4];
    #pragma unroll
    for (int i = 0; i < 4; i++)
        #pragma unroll
        for (int j = 0; j < 4; j++) acc[i][j] = fzero;

    float bv[4];
    #pragma unroll
    for (int cf = 0; cf < 4; cf++) bv[cf] = bias[n0 + wn * 64 + cf * 16 + l15];

    bf16x8 aF[4][2], bF[2][2];

// phase 0 of K-tile (buf CB): read A-frags (8) + B-quad0 (4), 16 MFMA
#define PH0(CB)                                                                    \
    {                                                                              \
        _Pragma("unroll")                                                          \
        for (int mc = 0; mc < 4; mc++)                                             \
            _Pragma("unroll")                                                      \
            for (int ks = 0; ks < 2; ks++)                                         \
                aF[mc][ks] = *(const bf16x8*)&sA[(CB) * 8192 +                     \
                    (wm * 64 + mc * 16 + l15) * 64 + (((ks * 4 + quad) ^ gx) * 8)];\
        _Pragma("unroll")                                                          \
        for (int nc = 0; nc < 2; nc++)                                             \
            _Pragma("unroll")                                                      \
            for (int ks = 0; ks < 2; ks++)                                         \
                bF[nc][ks] = *(const bf16x8*)&sB[(CB) * 16384 +                    \
                    (wn * 64 + nc * 16 + l15) * 64 + (((ks * 4 + quad) ^ gx) * 8)];\
        __builtin_amdgcn_s_barrier();                                              \
        __builtin_amdgcn_s_setprio(1);                                             \
        _Pragma("unroll")                                                          \
        for (int mc = 0; mc < 4; mc++)                                             \
            _Pragma("unroll")                                                      \
            for (int nc = 0; nc < 2; nc++)                                         \
                _Pragma("unroll")                                                  \
                for (int ks = 0; ks < 2; ks++)                                     \
                    acc[mc][nc] = mfma16(aF[mc][ks], bF[nc][ks], acc[mc][nc]);     \
        __builtin_amdgcn_s_setprio(0);                                             \
        __builtin_amdgcn_s_barrier();                                              \
    }

// phase 1: B-quad1 (4 reads, A-frags reused), 16 MFMA
#define PH1(CB)                                                                    \
    {                                                                              \
        _Pragma("unroll")                                                          \
        for (int nc = 0; nc < 2; nc++)                                             \
            _Pragma("unroll")                                                      \
            for (int ks = 0; ks < 2; ks++)                                         \
                bF[nc][ks] = *(const bf16x8*)&sB[(CB) * 16384 +                    \
                    (wn * 64 + 32 + nc * 16 + l15) * 64 +                          \
                    (((ks * 4 + quad) ^ gx) * 8)];                                 \
        __builtin_amdgcn_s_barrier();                                              \
        __builtin_amdgcn_s_setprio(1);                                             \
        _Pragma("unroll")                                                          \
        for (int mc = 0; mc < 4; mc++)                                             \
            _Pragma("unroll")                                                      \
            for (int nc = 0; nc < 2; nc++)                                         \
                _Pragma("unroll")                                                  \
                for (int ks = 0; ks < 2; ks++)                                     \
                    acc[mc][2 + nc] = mfma16(aF[mc][ks], bF[nc][ks], acc[mc][2 + nc]); \
        __builtin_amdgcn_s_setprio(0);                                             \
        __builtin_amdgcn_s_barrier();                                              \
    }

    // ---- prologue: tile0 fully + A of tile1; keep 2 loads in flight ----
    S_A(0, 0); S_A(1, 0);
    S_B(0, 0); S_B(1, 0); S_B(2, 0); S_B(3, 0);
    S_A(0, 1); S_A(1, 1);
    asm volatile("s_waitcnt vmcnt(2)" ::: "memory");
    __builtin_amdgcn_s_barrier();

    // ---- steady loop: tiles 0..13 (stages reach tile 15) ----
    for (int i = 0; i < 14; ++i) {
        const int cb = i & 1;
        S_B(0, i + 1); S_B(1, i + 1);
        __builtin_amdgcn_sched_barrier(0);
        PH0(cb);
        S_B(2, i + 1); S_B(3, i + 1);
        __builtin_amdgcn_sched_barrier(0);
        PH1(cb);
        S_A(0, i + 2); S_A(1, i + 2);
        asm volatile("s_waitcnt vmcnt(2)" ::: "memory");
        __builtin_amdgcn_s_barrier();
    }
    // ---- tile 14 (stage tile 15 B; then full drain) ----
    S_B(0, 15); S_B(1, 15);
    __builtin_amdgcn_sched_barrier(0);
    PH0(0);
    S_B(2, 15); S_B(3, 15);
    __builtin_amdgcn_sched_barrier(0);
    PH1(0);
    asm volatile("s_waitcnt vmcnt(0)" ::: "memory");
    __builtin_amdgcn_s_barrier();
    // ---- tile 15 (no staging) ----
    PH0(1);
    PH1(1);

#undef S_A
#undef S_B
#undef PH0
#undef PH1

    if (n0 >= 2048) {
        // ---- V block: transpose 128 tok x 256 dim via sB, write Vt ----
        __syncthreads();
        #pragma unroll
        for (int mc = 0; mc < 4; mc++)
            #pragma unroll
            for (int cf = 0; cf < 4; cf++) {
                int col = wn * 64 + cf * 16 + l15;       // dim 0..255
                int row = wm * 64 + mc * 16 + quad * 4;  // token 0..127
                bf16x4 v = {(bf16)(acc[mc][cf][0] + bv[cf]),
                            (bf16)(acc[mc][cf][1] + bv[cf]),
                            (bf16)(acc[mc][cf][2] + bv[cf]),
                            (bf16)(acc[mc][cf][3] + bv[cf])};
                *(bf16x4*)&sB[col * 128 + (row ^ ((col & 15) << 3))] = v;
            }
        __syncthreads();
        const int b = m0 >> 11, mloc = m0 & 2047;
        const int hp = (n0 - 2048) >> 6;
        #pragma unroll
        for (int it = 0; it < 16; it++) {
            int chunk = it * 512 + tid;                  // 0..8191
            int col = chunk >> 5;                        // 0..255
            int tok = (chunk & 31) * 4;
            bf16x4 v = *(const bf16x4*)&sB[col * 128 + (tok ^ ((col & 15) << 3))];
            int habs = hp + (col >> 6);
            int dd = col & 63;
            *(bf16x4*)&Vt[((size_t)((b * 16 + habs) * 64 + dd)) * 2048 + mloc + tok] = v;
        }
    } else {
        const float sc = (n0 < 1024) ? QSCALE : 1.0f;
        #pragma unroll
        for (int mc = 0; mc < 4; mc++) {
            #pragma unroll
            for (int reg = 0; reg < 4; reg++) {
                int row = m0 + wm * 64 + mc * 16 + quad * 4 + reg;
                size_t base = (size_t)row * N + n0 + wn * 64;
                #pragma unroll
                for (int cf = 0; cf < 4; cf++)
                    C[base + cf * 16 + l15] = (bf16)((acc[mc][cf][reg] + bv[cf]) * sc);
            }
        }
    }
}

// =====================================================================
// Out-projection GEMM (128-sq, T2 swizzle + 2-phase dbuf) — unchanged.
// =====================================================================
__global__ __launch_bounds__(256) void gemm_bf16_f32out_kernel(
    const bf16* __restrict__ A, const bf16* __restrict__ BT,
    const float* __restrict__ bias, float* __restrict__ C,
    int M, int N, int K)
{
    __shared__ bf16 sA[2][128 * 32];
    __shared__ bf16 sB[2][128 * 32];
    const int tid  = threadIdx.x;
    const int lane = tid & 63;
    const int wave = tid >> 6;
    const int quad = lane >> 4;
    const int l15  = lane & 15;
    const int wm = (wave >> 1) * 64;
    const int wn = (wave & 1) * 64;
    const int m0 = blockIdx.y * 128;
    const int n0 = blockIdx.x * 128;

    const f32x4 fzero = {0.f, 0.f, 0.f, 0.f};
    f32x4 acc[4][4];
    #pragma unroll
    for (int i = 0; i < 4; i++)
        #pragma unroll
        for (int j = 0; j < 4; j++) acc[i][j] = fzero;

    float bv[4];
    #pragma unroll
    for (int nc = 0; nc < 4; nc++) bv[nc] = bias[n0 + wn + nc * 16 + l15];

    const int rA = lane >> 2;
    const int cAsw = ((lane & 3) ^ ((lane >> 3) & 3)) * 8;
    const int gsw = (l15 >> 1) & 3;

#define GSTAGE(K0, BUF)                                                           \
    _Pragma("unroll")                                                             \
    for (int p = 0; p < 2; p++) {                                                 \
        int r16 = (wave * 2 + p) * 16;                                            \
        gll16(&A[(size_t)(m0 + r16 + rA) * K + (K0) + cAsw], &sA[BUF][r16 * 32]); \
        gll16(&BT[(size_t)(n0 + r16 + rA) * K + (K0) + cAsw], &sB[BUF][r16 * 32]);\
    }

#define GCOMPUTE(BUF)                                                             \
    {                                                                             \
        bf16x8 aF[4], bF[4];                                                      \
        _Pragma("unroll")                                                         \
        for (int mc = 0; mc < 4; mc++)                                            \
            aF[mc] = *(const bf16x8*)&sA[BUF][(wm + mc * 16 + l15) * 32 + ((quad ^ gsw) * 8)]; \
        _Pragma("unroll")                                                         \
        for (int nc = 0; nc < 4; nc++)                                            \
            bF[nc] = *(const bf16x8*)&sB[BUF][(wn + nc * 16 + l15) * 32 + ((quad ^ gsw) * 8)]; \
        _Pragma("unroll")                                                         \
        for (int mc = 0; mc < 4; mc++)                                            \
            _Pragma("unroll")                                                     \
            for (int nc = 0; nc < 4; nc++)                                        \
                acc[mc][nc] = mfma16(aF[mc], bF[nc], acc[mc][nc]);                \
    }

    GSTAGE(0, 0);
    __syncthreads();
    int buf = 0;
    for (int k0 = 0; k0 < K - 32; k0 += 32, buf ^= 1) {
        GSTAGE(k0 + 32, buf ^ 1);
        __builtin_amdgcn_sched_barrier(0);
        GCOMPUTE(buf);
        __syncthreads();
    }
    GCOMPUTE(buf);

#undef GSTAGE
#undef GCOMPUTE

    #pragma unroll
    for (int mc = 0; mc < 4; mc++) {
        #pragma unroll
        for (int reg = 0; reg < 4; reg++) {
            int row = m0 + wm + mc * 16 + quad * 4 + reg;
            size_t base = (size_t)row * N + n0 + wn;
            #pragma unroll
            for (int nc = 0; nc < 4; nc++)
                C[base + nc * 16 + l15] = acc[mc][nc][reg] + bv[nc];
        }
    }
}

// =====================================================================
// Flash attention — best measured variant (R5: 74.8us), unchanged.
// =====================================================================
__global__ __launch_bounds__(128, 2) void attn_kernel(
    const bf16* __restrict__ QKV, const bf16* __restrict__ Vt,
    bf16* __restrict__ Opre)
{
    __shared__ bf16 sK[2][64 * 64];      // [key][d], swizzled, double-buffered
    __shared__ bf16 sV[2][64 * 64];      // [d][key], swizzled, double-buffered

    const int tid  = threadIdx.x;
    const int lane = tid & 63;
    const int w    = tid >> 6;            // 0..1
    const int quad = lane >> 4;
    const int l15  = lane & 15;
    // XCD-chunked swizzle: grid=1024=8*128 (bijective).
    const int bid = (blockIdx.x & 7) * 128 + (blockIdx.x >> 3);
    const int bh = bid >> 4;        // 0..63
    const int qt = bid & 15;
    const int b = bh >> 4, h = bh & 15;
    const int q0 = qt * 128;

    // Q fragments as B-operand [n=q][k=d], four 16-row groups (Q pre-scaled)
    bf16x8 qF[4][2];
    #pragma unroll
    for (int g = 0; g < 4; g++) {
        size_t qrow = (size_t)(b * 2048 + q0 + w * 64 + g * 16 + l15) * 3072 + h * 64;
        qF[g][0] = *(const bf16x8*)&QKV[qrow + quad * 8];
        qF[g][1] = *(const bf16x8*)&QKV[qrow + 32 + quad * 8];
    }

    const f32x4 fzero = {0.f, 0.f, 0.f, 0.f};
    const bf16 one = (bf16)1.0f;
    const bf16x8 ones = {one, one, one, one, one, one, one, one};
    f32x4 ps[4] = {fzero, fzero, fzero, fzero};
    f32x4 o[4][4];
    #pragma unroll
    for (int g = 0; g < 4; g++)
        #pragma unroll
        for (int mt = 0; mt < 4; mt++) o[g][mt] = fzero;

    // staging: 128 threads, 64 rows x 8 granules, 4 rows/thread (stride 16)
    const int srow = tid >> 3, sseg = tid & 7;
    const size_t kbase = (size_t)(b * 2048) * 3072 + 1024 + h * 64;
    const size_t vbase = (size_t)bh * 64 * 2048;
    // swizzled granule for staging writes (p-invariant under row+=16)
    const int sgsw = sseg ^ ((srow & 3) | (((srow >> 3) & 1) << 2));

    // swizzle factors for compute reads (row-dependent parts are l15-only)
    const int swk = (l15 & 3) | (((l15 >> 2) & 1) << 2);  // for S^T K-rows
    const int swv = (l15 & 3) | (((l15 >> 3) & 1) << 2);  // for V rows mt*16+l15

    bf16x8 stK[4], stV[4];    // in-flight staging regs (next tile)

#define ISSUE(KEY0)                                                               \
    _Pragma("unroll")                                                             \
    for (int p = 0; p < 4; p++) {                                                 \
        int row = srow + p * 16;                                                  \
        stK[p] = *(const bf16x8*)&QKV[kbase + (size_t)((KEY0) + row) * 3072 + sseg * 8]; \
        stV[p] = *(const bf16x8*)&Vt[vbase + (size_t)row * 2048 + (KEY0) + sseg * 8];    \
    }

#define COMMIT(BUF)                                                               \
    _Pragma("unroll")                                                             \
    for (int p = 0; p < 4; p++) {                                                 \
        int row = srow + p * 16;                                                  \
        *(bf16x8*)&sK[BUF][row * 64 + sgsw * 8] = stK[p];                         \
        *(bf16x8*)&sV[BUF][row * 64 + sgsw * 8] = stV[p];                         \
    }

    auto compute_tile = [&](const bf16* sKc, const bf16* sVc) {
        bf16x8 pB[4][2];
        __builtin_amdgcn_s_setprio(1);
        // ---- QK^T keys 0..31 (c=0,1) -> pB[*][0]
        #pragma unroll
        for (int c = 0; c < 2; c++) {
            int kr = ((l15 >> 2) << 3) + (c << 2) + (l15 & 3);
            bf16x8 kA0 = *(const bf16x8*)&sKc[kr * 64 + ((quad ^ swk) * 8)];
            bf16x8 kA1 = *(const bf16x8*)&sKc[kr * 64 + (((4 + quad) ^ swk) * 8)];
            #pragma unroll
            for (int g = 0; g < 4; g++) {
                f32x4 st = mfma16(kA0, qF[g][0], fzero);
                st = mfma16(kA1, qF[g][1], st);
                #pragma unroll
                for (int r = 0; r < 4; r++) {
                    float p = __builtin_amdgcn_exp2f(st[r]);
                    pB[g][0][c * 4 + r] = (bf16)p;
                }
            }
        }
        // ---- V k-slot-0 fragments (for PV half 0)
        bf16x8 vA0[4];
        #pragma unroll
        for (int mt = 0; mt < 4; mt++)
            vA0[mt] = *(const bf16x8*)&sVc[(mt * 16 + l15) * 64 + ((quad ^ swv) * 8)];
        // ---- QK^T keys 32..63 (c=2,3) -> pB[*][1]   (independent of PV0)
        #pragma unroll
        for (int c = 0; c < 2; c++) {
            int kr = ((l15 >> 2) << 3) + (c << 2) + (l15 & 3) + 32;
            bf16x8 kA0 = *(const bf16x8*)&sKc[kr * 64 + ((quad ^ swk) * 8)];
            bf16x8 kA1 = *(const bf16x8*)&sKc[kr * 64 + (((4 + quad) ^ swk) * 8)];
            #pragma unroll
            for (int g = 0; g < 4; g++) {
                f32x4 st = mfma16(kA0, qF[g][0], fzero);
                st = mfma16(kA1, qF[g][1], st);
                #pragma unroll
                for (int r = 0; r < 4; r++) {
                    float p = __builtin_amdgcn_exp2f(st[r]);
                    pB[g][1][c * 4 + r] = (bf16)p;
                }
            }
        }
        // ---- PV half 0 + psum half 0 (keys 0..31; overlaps QKT above)
        #pragma unroll
        for (int g = 0; g < 4; g++) ps[g] = mfma16(ones, pB[g][0], ps[g]);
        #pragma unroll
        for (int mt = 0; mt < 4; mt++)
            #pragma unroll
            for (int g = 0; g < 4; g++)
                o[g][mt] = mfma16(vA0[mt], pB[g][0], o[g][mt]);
        // ---- PV half 1 + psum half 1 (keys 32..63)
        bf16x8 vA1[4];
        #pragma unroll
        for (int mt = 0; mt < 4; mt++)
            vA1[mt] = *(const bf16x8*)&sVc[(mt * 16 + l15) * 64 + (((4 + quad) ^ swv) * 8)];
        #pragma unroll
        for (int g = 0; g < 4; g++) ps[g] = mfma16(ones, pB[g][1], ps[g]);
        #pragma unroll
        for (int mt = 0; mt < 4; mt++)
            #pragma unroll
            for (int g = 0; g < 4; g++)
                o[g][mt] = mfma16(vA1[mt], pB[g][1], o[g][mt]);
        __builtin_amdgcn_s_setprio(0);
    };

    // ---- prologue: stage tile 0 into buffer 0 ----
    ISSUE(0);
    COMMIT(0);
    __syncthreads();

    // ---- main loop: issue t+1 early, compute t, commit t+1, barrier ----
    for (int t = 0; t < 31; t++) {
        ISSUE((t + 1) * 64);
        __builtin_amdgcn_sched_barrier(0);   // pin loads above compute
        compute_tile(sK[t & 1], sV[t & 1]);
        COMMIT((t + 1) & 1);                 // vmcnt wait covered by compute
        __syncthreads();
    }
    compute_tile(sK[1], sV[1]);              // tile 31 (odd -> buf1)

#undef ISSUE
#undef COMMIT

    // psum is complete per-lane (MFMA reduced over all keys); all ps regs equal
    #pragma unroll
    for (int g = 0; g < 4; g++) {
        float inv = 1.0f / ps[g][0];
        size_t obase = (size_t)(b * 2048 + q0 + w * 64 + g * 16 + l15) * 1024 + h * 64;
        #pragma unroll
        for (int mt = 0; mt < 4; mt++) {
            bf16x4 ov = {(bf16)(o[g][mt][0] * inv), (bf16)(o[g][mt][1] * inv),
                         (bf16)(o[g][mt][2] * inv), (bf16)(o[g][mt][3] * inv)};
            *(bf16x4*)&Opre[obase + mt * 16 + quad * 4] = ov;
        }
    }
}

// =====================================================================
extern "C" void kernel_launch(void* const* d_in, const int* in_sizes, int n_in,
                              void* d_out, int out_size, void* d_ws, size_t ws_size,
                              hipStream_t stream)
{
    const float* x  = (const float*)d_in[0];
    const float* Wq = (const float*)d_in[1];
    const float* bq = (const float*)d_in[2];
    const float* Wk = (const float*)d_in[3];
    const float* bk = (const float*)d_in[4];
    const float* Wv = (const float*)d_in[5];
    const float* bv = (const float*)d_in[6];
    const float* Wo = (const float*)d_in[7];
    const float* bo = (const float*)d_in[8];
    float* out = (float*)d_out;

    bf16* WTqkv = (bf16*)d_ws;                         // 3072*1024 bf16
    bf16* WTo   = WTqkv + (size_t)3072 * 1024;         // 1024*1024 bf16
    float* bcat = (float*)(WTo + (size_t)1024 * 1024); // 3072 f32 (pad 4096)
    bf16* QKVp  = (bf16*)(bcat + 4096);                // 8192*3072 bf16
    bf16* Vt    = QKVp + (size_t)8192 * 3072;          // 64*64*2048 bf16
    bf16* Apre  = Vt + (size_t)64 * 64 * 2048;         // 8192*1024 bf16
    bf16* xb    = Apre;   // alias: x-as-bf16 lives here until attn overwrites
    (void)ws_size; (void)n_in; (void)in_sizes; (void)out_size;

    prep_kernel<<<5132, 256, 0, stream>>>(x, xb, Wq, Wk, Wv, Wo, WTqkv, WTo,
                                          bq, bk, bv, bcat);
    gemm_qkv_kernel<<<dim3(12, 64), 512, 0, stream>>>(xb, WTqkv, bcat, QKVp, Vt);
    attn_kernel<<<1024, 128, 0, stream>>>(QKVp, Vt, Apre);
    gemm_bf16_f32out_kernel<<<dim3(8, 64), 256, 0, stream>>>(Apre, WTo, bo, out, 8192, 1024, 1024);
}

// Round 12
// 269.859 us; speedup vs baseline: 1.0615x; 1.0615x over previous
//
#include <hip/hip_runtime.h>

typedef __bf16 bf16;
typedef __attribute__((ext_vector_type(8))) __bf16 bf16x8;
typedef __attribute__((ext_vector_type(4))) __bf16 bf16x4;
typedef __attribute__((ext_vector_type(4))) float f32x4;

static __device__ __forceinline__ f32x4 mfma16(bf16x8 a, bf16x8 b, f32x4 c) {
    return __builtin_amdgcn_mfma_f32_16x16x32_bf16(a, b, c, 0, 0, 0);
}

// async global->LDS, 16B per lane; lds base must be wave-uniform
static __device__ __forceinline__ void gll16(const bf16* g, bf16* l) {
    __builtin_amdgcn_global_load_lds(
        (const __attribute__((address_space(1))) unsigned int*)g,
        (__attribute__((address_space(3))) unsigned int*)l, 16, 0, 0);
}

// =====================================================================
// Fused prep: xcvt (blocks 0..4095) | wtrans (4096..5119) | biascat (5120..5131)
// =====================================================================
__global__ __launch_bounds__(256) void prep_kernel(
    const float* __restrict__ x, bf16* __restrict__ xb,
    const float* __restrict__ Wq, const float* __restrict__ Wk,
    const float* __restrict__ Wv, const float* __restrict__ Wo,
    bf16* __restrict__ WTqkv, bf16* __restrict__ WTo,
    const float* __restrict__ bq, const float* __restrict__ bk,
    const float* __restrict__ bv, float* __restrict__ bcat)
{
    __shared__ bf16 tile[64][65];
    const int bid = blockIdx.x;
    const int tid = threadIdx.x;

    if (bid < 4096) {
        size_t i = ((size_t)bid * 256 + tid) * 8;
        float4 a0 = *(const float4*)&x[i];
        float4 a1 = *(const float4*)&x[i + 4];
        bf16x8 v = {(bf16)a0.x, (bf16)a0.y, (bf16)a0.z, (bf16)a0.w,
                    (bf16)a1.x, (bf16)a1.y, (bf16)a1.z, (bf16)a1.w};
        *(bf16x8*)&xb[i] = v;
    } else if (bid < 5120) {
        const int wb = bid - 4096;
        const int mi = wb >> 8;
        const int t  = wb & 255;
        const int tr = t >> 4;
        const int tc = t & 15;
        const float* src = (mi == 0) ? Wq : (mi == 1) ? Wk : (mi == 2) ? Wv : Wo;
        bf16* dst = (mi < 3) ? (WTqkv + (size_t)mi * 1024 * 1024) : WTo;

        #pragma unroll
        for (int i = 0; i < 16; i++) {
            int idx = i * 256 + tid;
            int rl = idx >> 6, cl = idx & 63;
            tile[rl][cl] = (bf16)src[(size_t)(tr * 64 + rl) * 1024 + tc * 64 + cl];
        }
        __syncthreads();
        #pragma unroll
        for (int i = 0; i < 16; i++) {
            int idx = i * 256 + tid;
            int rl = idx >> 6, cl = idx & 63;
            dst[(size_t)(tc * 64 + rl) * 1024 + tr * 64 + cl] = tile[cl][rl];
        }
    } else {
        int i = (bid - 5120) * 256 + tid;
        if (i < 1024) bcat[i] = bq[i];
        else if (i < 2048) bcat[i] = bk[i - 1024];
        else if (i < 3072) bcat[i] = bv[i - 2048];
    }
}

// =====================================================================
// QKV GEMM — verified R9 form (128x128, T2 swizzle, 2-phase dbuf,
// 3 blocks/CU cross-block overlap) with fused V-transpose epilogue.
// =====================================================================
#define QSCALE 0.18033688011112043f   // 0.125 * log2(e)
__global__ __launch_bounds__(256) void gemm_bf16_kernel(
    const bf16* __restrict__ A, const bf16* __restrict__ BT,
    const float* __restrict__ bias, bf16* __restrict__ C,
    bf16* __restrict__ Vt, int M, int N, int K)
{
    __shared__ bf16 smem[16384];          // sA/sB staging; reused for V-transpose

    const int tid  = threadIdx.x;
    const int lane = tid & 63;
    const int wave = tid >> 6;
    const int quad = lane >> 4;
    const int l15  = lane & 15;
    const int wm = (wave >> 1) * 64;
    const int wn = (wave & 1) * 64;
    const int m0 = blockIdx.y * 128;
    const int n0 = blockIdx.x * 128;

    const f32x4 fzero = {0.f, 0.f, 0.f, 0.f};
    f32x4 acc[4][4];
    #pragma unroll
    for (int i = 0; i < 4; i++)
        #pragma unroll
        for (int j = 0; j < 4; j++) acc[i][j] = fzero;

    float bv[4];
    #pragma unroll
    for (int nc = 0; nc < 4; nc++) bv[nc] = bias[n0 + wn + nc * 16 + l15];

    const int rA = lane >> 2;
    const int cAsw = ((lane & 3) ^ ((lane >> 3) & 3)) * 8;   // pre-swizzled src col
    const int gsw = (l15 >> 1) & 3;                          // read granule swizzle

// sA buf at smem + BUF*4096, sB buf at smem + 8192 + BUF*4096
#define GSTAGE(K0, BUF)                                                           \
    _Pragma("unroll")                                                             \
    for (int p = 0; p < 2; p++) {                                                 \
        int r16 = (wave * 2 + p) * 16;                                            \
        gll16(&A[(size_t)(m0 + r16 + rA) * K + (K0) + cAsw],                      \
              &smem[(BUF) * 4096 + r16 * 32]);                                    \
        gll16(&BT[(size_t)(n0 + r16 + rA) * K + (K0) + cAsw],                     \
              &smem[8192 + (BUF) * 4096 + r16 * 32]);                             \
    }

#define GCOMPUTE(BUF)                                                             \
    {                                                                             \
        bf16x8 aF[4], bF[4];                                                      \
        _Pragma("unroll")                                                         \
        for (int mc = 0; mc < 4; mc++)                                            \
            aF[mc] = *(const bf16x8*)&smem[(BUF) * 4096 +                         \
                     (wm + mc * 16 + l15) * 32 + ((quad ^ gsw) * 8)];             \
        _Pragma("unroll")                                                         \
        for (int nc = 0; nc < 4; nc++)                                            \
            bF[nc] = *(const bf16x8*)&smem[8192 + (BUF) * 4096 +                  \
                     (wn + nc * 16 + l15) * 32 + ((quad ^ gsw) * 8)];             \
        _Pragma("unroll")                                                         \
        for (int mc = 0; mc < 4; mc++)                                            \
            _Pragma("unroll")                                                     \
            for (int nc = 0; nc < 4; nc++)                                        \
                acc[mc][nc] = mfma16(aF[mc], bF[nc], acc[mc][nc]);                \
    }

    GSTAGE(0, 0);
    __syncthreads();
    int buf = 0;
    for (int k0 = 0; k0 < K - 32; k0 += 32, buf ^= 1) {
        GSTAGE(k0 + 32, buf ^ 1);
        __builtin_amdgcn_sched_barrier(0);   // keep stage issue above compute
        GCOMPUTE(buf);
        __syncthreads();                     // vmcnt drain: one phase after issue
    }
    GCOMPUTE(buf);                           // last tile

    if (n0 >= 2048) {
        // ---- V block: transpose via LDS, write Vt[bh][d][token] ----
        __syncthreads();                     // all waves done reading smem
        #pragma unroll
        for (int mc = 0; mc < 4; mc++)
            #pragma unroll
            for (int nc = 0; nc < 4; nc++) {
                int col = wn + nc * 16 + l15;
                int row = wm + mc * 16 + quad * 4;
                bf16x4 v = {(bf16)(acc[mc][nc][0] + bv[nc]),
                            (bf16)(acc[mc][nc][1] + bv[nc]),
                            (bf16)(acc[mc][nc][2] + bv[nc]),
                            (bf16)(acc[mc][nc][3] + bv[nc])};
                *(bf16x4*)&smem[col * 128 + (row ^ ((col & 15) << 3))] = v;
            }
        __syncthreads();
        const int b = m0 >> 11, mloc = m0 & 2047;
        const int hp = (n0 - 2048) >> 6;     // first absolute head of this tile
        #pragma unroll
        for (int it = 0; it < 16; it++) {
            int e = it * 256 + tid;
            int col = e >> 5;                // 0..127
            int tok = (e & 31) * 4;
            bf16x4 v = *(const bf16x4*)&smem[col * 128 + (tok ^ ((col & 15) << 3))];
            int habs = hp + (col >> 6);
            int dd = col & 63;
            *(bf16x4*)&Vt[((size_t)((b * 16 + habs) * 64 + dd)) * 2048 + mloc + tok] = v;
        }
    } else {
        const float sc = (n0 < 1024) ? QSCALE : 1.0f;
        #pragma unroll
        for (int mc = 0; mc < 4; mc++) {
            #pragma unroll
            for (int reg = 0; reg < 4; reg++) {
                int row = m0 + wm + mc * 16 + quad * 4 + reg;
                size_t base = (size_t)row * N + n0 + wn;
                #pragma unroll
                for (int nc = 0; nc < 4; nc++)
                    C[base + nc * 16 + l15] = (bf16)((acc[mc][nc][reg] + bv[nc]) * sc);
            }
        }
    }
#undef GSTAGE
#undef GCOMPUTE
}

// =====================================================================
// Out-projection GEMM — BM 64 (tile 64x128), grid (8,128)=1024 blocks
// = 4 blocks/CU for cross-block overlap of the barrier drain.
// =====================================================================
__global__ __launch_bounds__(256, 4) void gemm_bf16_f32out_kernel(
    const bf16* __restrict__ A, const bf16* __restrict__ BT,
    const float* __restrict__ bias, float* __restrict__ C,
    int M, int N, int K)
{
    __shared__ bf16 sA[2][64 * 32];
    __shared__ bf16 sB[2][128 * 32];
    const int tid  = threadIdx.x;
    const int lane = tid & 63;
    const int wave = tid >> 6;        // 0..3
    const int quad = lane >> 4;
    const int l15  = lane & 15;
    const int wm = (wave >> 1) * 32;  // 0 or 32
    const int wn = (wave & 1) * 64;   // 0 or 64
    const int m0 = blockIdx.y * 64;
    const int n0 = blockIdx.x * 128;

    const f32x4 fzero = {0.f, 0.f, 0.f, 0.f};
    f32x4 acc[2][4];
    #pragma unroll
    for (int i = 0; i < 2; i++)
        #pragma unroll
        for (int j = 0; j < 4; j++) acc[i][j] = fzero;

    float bv[4];
    #pragma unroll
    for (int nc = 0; nc < 4; nc++) bv[nc] = bias[n0 + wn + nc * 16 + l15];

    const int rA = lane >> 2;
    const int cAsw = ((lane & 3) ^ ((lane >> 3) & 3)) * 8;
    const int gsw = (l15 >> 1) & 3;

// A: 64x32 tile, 1 load/thread (row wave*16+rA); B: 128x32, 2 loads/thread
#define GSTAGE(K0, BUF)                                                           \
    gll16(&A[(size_t)(m0 + wave * 16 + rA) * K + (K0) + cAsw],                    \
          &sA[BUF][wave * 16 * 32]);                                              \
    _Pragma("unroll")                                                             \
    for (int p = 0; p < 2; p++) {                                                 \
        int r16 = (wave * 2 + p) * 16;                                            \
        gll16(&BT[(size_t)(n0 + r16 + rA) * K + (K0) + cAsw], &sB[BUF][r16 * 32]);\
    }

#define GCOMPUTE(BUF)                                                             \
    {                                                                             \
        bf16x8 aF[2], bF[4];                                                      \
        _Pragma("unroll")                                                         \
        for (int mc = 0; mc < 2; mc++)                                            \
            aF[mc] = *(const bf16x8*)&sA[BUF][(wm + mc * 16 + l15) * 32 + ((quad ^ gsw) * 8)]; \
        _Pragma("unroll")                                                         \
        for (int nc = 0; nc < 4; nc++)                                            \
            bF[nc] = *(const bf16x8*)&sB[BUF][(wn + nc * 16 + l15) * 32 + ((quad ^ gsw) * 8)]; \
        _Pragma("unroll")                                                         \
        for (int mc = 0; mc < 2; mc++)                                            \
            _Pragma("unroll")                                                     \
            for (int nc = 0; nc < 4; nc++)                                        \
                acc[mc][nc] = mfma16(aF[mc], bF[nc], acc[mc][nc]);                \
    }

    GSTAGE(0, 0);
    __syncthreads();
    int buf = 0;
    for (int k0 = 0; k0 < K - 32; k0 += 32, buf ^= 1) {
        GSTAGE(k0 + 32, buf ^ 1);
        __builtin_amdgcn_sched_barrier(0);
        GCOMPUTE(buf);
        __syncthreads();
    }
    GCOMPUTE(buf);

#undef GSTAGE
#undef GCOMPUTE

    #pragma unroll
    for (int mc = 0; mc < 2; mc++) {
        #pragma unroll
        for (int reg = 0; reg < 4; reg++) {
            int row = m0 + wm + mc * 16 + quad * 4 + reg;
            size_t base = (size_t)row * N + n0 + wn;
            #pragma unroll
            for (int nc = 0; nc < 4; nc++)
                C[base + nc * 16 + l15] = acc[mc][nc][reg] + bv[nc];
        }
    }
}

// =====================================================================
// Flash attention — best measured variant (R5: 74.8us), unchanged.
// =====================================================================
__global__ __launch_bounds__(128, 2) void attn_kernel(
    const bf16* __restrict__ QKV, const bf16* __restrict__ Vt,
    bf16* __restrict__ Opre)
{
    __shared__ bf16 sK[2][64 * 64];      // [key][d], swizzled, double-buffered
    __shared__ bf16 sV[2][64 * 64];      // [d][key], swizzled, double-buffered

    const int tid  = threadIdx.x;
    const int lane = tid & 63;
    const int w    = tid >> 6;            // 0..1
    const int quad = lane >> 4;
    const int l15  = lane & 15;
    // XCD-chunked swizzle: grid=1024=8*128 (bijective).
    const int bid = (blockIdx.x & 7) * 128 + (blockIdx.x >> 3);
    const int bh = bid >> 4;        // 0..63
    const int qt = bid & 15;
    const int b = bh >> 4, h = bh & 15;
    const int q0 = qt * 128;

    // Q fragments as B-operand [n=q][k=d], four 16-row groups (Q pre-scaled)
    bf16x8 qF[4][2];
    #pragma unroll
    for (int g = 0; g < 4; g++) {
        size_t qrow = (size_t)(b * 2048 + q0 + w * 64 + g * 16 + l15) * 3072 + h * 64;
        qF[g][0] = *(const bf16x8*)&QKV[qrow + quad * 8];
        qF[g][1] = *(const bf16x8*)&QKV[qrow + 32 + quad * 8];
    }

    const f32x4 fzero = {0.f, 0.f, 0.f, 0.f};
    const bf16 one = (bf16)1.0f;
    const bf16x8 ones = {one, one, one, one, one, one, one, one};
    f32x4 ps[4] = {fzero, fzero, fzero, fzero};
    f32x4 o[4][4];
    #pragma unroll
    for (int g = 0; g < 4; g++)
        #pragma unroll
        for (int mt = 0; mt < 4; mt++) o[g][mt] = fzero;

    // staging: 128 threads, 64 rows x 8 granules, 4 rows/thread (stride 16)
    const int srow = tid >> 3, sseg = tid & 7;
    const size_t kbase = (size_t)(b * 2048) * 3072 + 1024 + h * 64;
    const size_t vbase = (size_t)bh * 64 * 2048;
    // swizzled granule for staging writes (p-invariant under row+=16)
    const int sgsw = sseg ^ ((srow & 3) | (((srow >> 3) & 1) << 2));

    // swizzle factors for compute reads (row-dependent parts are l15-only)
    const int swk = (l15 & 3) | (((l15 >> 2) & 1) << 2);  // for S^T K-rows
    const int swv = (l15 & 3) | (((l15 >> 3) & 1) << 2);  // for V rows mt*16+l15

    bf16x8 stK[4], stV[4];    // in-flight staging regs (next tile)

#define ISSUE(KEY0)                                                               \
    _Pragma("unroll")                                                             \
    for (int p = 0; p < 4; p++) {                                                 \
        int row = srow + p * 16;                                                  \
        stK[p] = *(const bf16x8*)&QKV[kbase + (size_t)((KEY0) + row) * 3072 + sseg * 8]; \
        stV[p] = *(const bf16x8*)&Vt[vbase + (size_t)row * 2048 + (KEY0) + sseg * 8];    \
    }

#define COMMIT(BUF)                                                               \
    _Pragma("unroll")                                                             \
    for (int p = 0; p < 4; p++) {                                                 \
        int row = srow + p * 16;                                                  \
        *(bf16x8*)&sK[BUF][row * 64 + sgsw * 8] = stK[p];                         \
        *(bf16x8*)&sV[BUF][row * 64 + sgsw * 8] = stV[p];                         \
    }

    auto compute_tile = [&](const bf16* sKc, const bf16* sVc) {
        bf16x8 pB[4][2];
        __builtin_amdgcn_s_setprio(1);
        // ---- QK^T keys 0..31 (c=0,1) -> pB[*][0]
        #pragma unroll
        for (int c = 0; c < 2; c++) {
            int kr = ((l15 >> 2) << 3) + (c << 2) + (l15 & 3);
            bf16x8 kA0 = *(const bf16x8*)&sKc[kr * 64 + ((quad ^ swk) * 8)];
            bf16x8 kA1 = *(const bf16x8*)&sKc[kr * 64 + (((4 + quad) ^ swk) * 8)];
            #pragma unroll
            for (int g = 0; g < 4; g++) {
                f32x4 st = mfma16(kA0, qF[g][0], fzero);
                st = mfma16(kA1, qF[g][1], st);
                #pragma unroll
                for (int r = 0; r < 4; r++) {
                    float p = __builtin_amdgcn_exp2f(st[r]);
                    pB[g][0][c * 4 + r] = (bf16)p;
                }
            }
        }
        // ---- V k-slot-0 fragments (for PV half 0)
        bf16x8 vA0[4];
        #pragma unroll
        for (int mt = 0; mt < 4; mt++)
            vA0[mt] = *(const bf16x8*)&sVc[(mt * 16 + l15) * 64 + ((quad ^ swv) * 8)];
        // ---- QK^T keys 32..63 (c=2,3) -> pB[*][1]   (independent of PV0)
        #pragma unroll
        for (int c = 0; c < 2; c++) {
            int kr = ((l15 >> 2) << 3) + (c << 2) + (l15 & 3) + 32;
            bf16x8 kA0 = *(const bf16x8*)&sKc[kr * 64 + ((quad ^ swk) * 8)];
            bf16x8 kA1 = *(const bf16x8*)&sKc[kr * 64 + (((4 + quad) ^ swk) * 8)];
            #pragma unroll
            for (int g = 0; g < 4; g++) {
                f32x4 st = mfma16(kA0, qF[g][0], fzero);
                st = mfma16(kA1, qF[g][1], st);
                #pragma unroll
                for (int r = 0; r < 4; r++) {
                    float p = __builtin_amdgcn_exp2f(st[r]);
                    pB[g][1][c * 4 + r] = (bf16)p;
                }
            }
        }
        // ---- PV half 0 + psum half 0 (keys 0..31; overlaps QKT above)
        #pragma unroll
        for (int g = 0; g < 4; g++) ps[g] = mfma16(ones, pB[g][0], ps[g]);
        #pragma unroll
        for (int mt = 0; mt < 4; mt++)
            #pragma unroll
            for (int g = 0; g < 4; g++)
                o[g][mt] = mfma16(vA0[mt], pB[g][0], o[g][mt]);
        // ---- PV half 1 + psum half 1 (keys 32..63)
        bf16x8 vA1[4];
        #pragma unroll
        for (int mt = 0; mt < 4; mt++)
            vA1[mt] = *(const bf16x8*)&sVc[(mt * 16 + l15) * 64 + (((4 + quad) ^ swv) * 8)];
        #pragma unroll
        for (int g = 0; g < 4; g++) ps[g] = mfma16(ones, pB[g][1], ps[g]);
        #pragma unroll
        for (int mt = 0; mt < 4; mt++)
            #pragma unroll
            for (int g = 0; g < 4; g++)
                o[g][mt] = mfma16(vA1[mt], pB[g][1], o[g][mt]);
        __builtin_amdgcn_s_setprio(0);
    };

    // ---- prologue: stage tile 0 into buffer 0 ----
    ISSUE(0);
    COMMIT(0);
    __syncthreads();

    // ---- main loop: issue t+1 early, compute t, commit t+1, barrier ----
    for (int t = 0; t < 31; t++) {
        ISSUE((t + 1) * 64);
        __builtin_amdgcn_sched_barrier(0);   // pin loads above compute
        compute_tile(sK[t & 1], sV[t & 1]);
        COMMIT((t + 1) & 1);                 // vmcnt wait covered by compute
        __syncthreads();
    }
    compute_tile(sK[1], sV[1]);              // tile 31 (odd -> buf1)

#undef ISSUE
#undef COMMIT

    // psum is complete per-lane (MFMA reduced over all keys); all ps regs equal
    #pragma unroll
    for (int g = 0; g < 4; g++) {
        float inv = 1.0f / ps[g][0];
        size_t obase = (size_t)(b * 2048 + q0 + w * 64 + g * 16 + l15) * 1024 + h * 64;
        #pragma unroll
        for (int mt = 0; mt < 4; mt++) {
            bf16x4 ov = {(bf16)(o[g][mt][0] * inv), (bf16)(o[g][mt][1] * inv),
                         (bf16)(o[g][mt][2] * inv), (bf16)(o[g][mt][3] * inv)};
            *(bf16x4*)&Opre[obase + mt * 16 + quad * 4] = ov;
        }
    }
}

// =====================================================================
extern "C" void kernel_launch(void* const* d_in, const int* in_sizes, int n_in,
                              void* d_out, int out_size, void* d_ws, size_t ws_size,
                              hipStream_t stream)
{
    const float* x  = (const float*)d_in[0];
    const float* Wq = (const float*)d_in[1];
    const float* bq = (const float*)d_in[2];
    const float* Wk = (const float*)d_in[3];
    const float* bk = (const float*)d_in[4];
    const float* Wv = (const float*)d_in[5];
    const float* bv = (const float*)d_in[6];
    const float* Wo = (const float*)d_in[7];
    const float* bo = (const float*)d_in[8];
    float* out = (float*)d_out;

    bf16* WTqkv = (bf16*)d_ws;                         // 3072*1024 bf16
    bf16* WTo   = WTqkv + (size_t)3072 * 1024;         // 1024*1024 bf16
    float* bcat = (float*)(WTo + (size_t)1024 * 1024); // 3072 f32 (pad 4096)
    bf16* QKVp  = (bf16*)(bcat + 4096);                // 8192*3072 bf16
    bf16* Vt    = QKVp + (size_t)8192 * 3072;          // 64*64*2048 bf16
    bf16* Apre  = Vt + (size_t)64 * 64 * 2048;         // 8192*1024 bf16
    bf16* xb    = Apre;   // alias: x-as-bf16 lives here until attn overwrites
    (void)ws_size; (void)n_in; (void)in_sizes; (void)out_size;

    prep_kernel<<<5132, 256, 0, stream>>>(x, xb, Wq, Wk, Wv, Wo, WTqkv, WTo,
                                          bq, bk, bv, bcat);
    gemm_bf16_kernel<<<dim3(24, 64), 256, 0, stream>>>(xb, WTqkv, bcat, QKVp, Vt, 8192, 3072, 1024);
    attn_kernel<<<1024, 128, 0, stream>>>(QKVp, Vt, Apre);
    gemm_bf16_f32out_kernel<<<dim3(8, 128), 256, 0, stream>>>(Apre, WTo, bo, out, 8192, 1024, 1024);
}